// Round 4
// baseline (1126.046 us; speedup 1.0000x reference)
//
#include <hip/hip_runtime.h>
#include <hip/hip_bf16.h>

typedef _Float16 h2v __attribute__((ext_vector_type(2)));

#define B_SZ 64
#define T_SZ 512
#define E_SZ 256
#define H_SZ 256
#define C_SZ 768   // 3*H

__device__ __forceinline__ float dot2f(h2v a, h2v b, float c) {
#if __has_builtin(__builtin_amdgcn_fdot2)
  return __builtin_amdgcn_fdot2(a, b, c, false);
#else
  return c + (float)a[0] * (float)b[0] + (float)a[1] * (float)b[1];
#endif
}

__device__ __forceinline__ float rcp_fast(float x) {
  return __builtin_amdgcn_rcpf(x);
}

// ---------------------------------------------------------------------------
// Kernel 1: xp[dir][row][c] = (emb[x[row]] @ kernel_dir)[c] + bias_dir[0][c]
// rows = b*T + t (32768 per dir), cols = 768, K = 256.  Tile 64x48, 256 thr.
// ---------------------------------------------------------------------------
__global__ __launch_bounds__(256) void xp_gemm_kernel(
    const int* __restrict__ x,
    const float* __restrict__ emb,
    const float* __restrict__ kf, const float* __restrict__ bf,
    const float* __restrict__ kb, const float* __restrict__ bb,
    _Float16* __restrict__ xp)
{
  const int ct  = blockIdx.x;   // 16 col tiles of 48
  const int rt  = blockIdx.y;   // 512 row tiles of 64
  const int dir = blockIdx.z;
  const float* Kp = dir ? kb : kf;
  const float* Bp = dir ? bb : bf;
  const int c0 = ct * 48;
  const int r0 = rt * 64;
  const int tid = threadIdx.x;

  __shared__ __align__(16) _Float16 As[64][264];  // 264 = 256 + 8 pad (16B-aligned rows)
  __shared__ __align__(16) _Float16 Bs[48][264];

  // stage A: gathered embedding rows (k = tid, one row per iter; x[] is wave-uniform)
  for (int r = 0; r < 64; ++r) {
    int xi = x[r0 + r];
    As[r][tid] = (_Float16)emb[(size_t)xi * E_SZ + tid];
  }
  // stage B^T: Bs[c][k] = K[k][c0+c]
  for (int i = tid; i < 48 * 256; i += 256) {
    int k = i / 48;
    int c = i - k * 48;
    Bs[c][k] = (_Float16)Kp[k * C_SZ + c0 + c];
  }
  __syncthreads();

  const int tr = tid >> 4;   // 0..15 -> rows {4*tr+i}
  const int tc = tid & 15;   // 0..15 -> cols {tc+16*j}
  float acc[4][3];
  #pragma unroll
  for (int i = 0; i < 4; ++i)
    #pragma unroll
    for (int j = 0; j < 3; ++j) acc[i][j] = 0.f;

  #pragma unroll
  for (int m = 0; m < 32; ++m) {        // k = 8*m
    float4 a4[4], b4[3];
    #pragma unroll
    for (int i = 0; i < 4; ++i) a4[i] = *(const float4*)&As[tr * 4 + i][m * 8];
    #pragma unroll
    for (int j = 0; j < 3; ++j) b4[j] = *(const float4*)&Bs[tc + 16 * j][m * 8];
    #pragma unroll
    for (int i = 0; i < 4; ++i) {
      const h2v* ah = (const h2v*)&a4[i];
      #pragma unroll
      for (int j = 0; j < 3; ++j) {
        const h2v* bh = (const h2v*)&b4[j];
        #pragma unroll
        for (int p = 0; p < 4; ++p) acc[i][j] = dot2f(ah[p], bh[p], acc[i][j]);
      }
    }
  }

  #pragma unroll
  for (int j = 0; j < 3; ++j) {
    int c = c0 + tc + 16 * j;
    float bias = Bp[c];                 // bias row 0
    #pragma unroll
    for (int i = 0; i < 4; ++i) {
      int r = r0 + tr * 4 + i;
      xp[((size_t)dir * (B_SZ * T_SZ) + r) * C_SZ + c] = (_Float16)(acc[i][j] + bias);
    }
  }
}

// ---------------------------------------------------------------------------
// Kernel 2: the GRU scan. One (batch, dir) chain per WG; 768 threads.
// Thread j owns column j of rkernel (128 f16 pairs in VGPRs).
// h broadcast through LDS as f16; carried state kept in f32 registers.
// VGPR audit: col[]=128 + prefetch 6 + q 4 + misc ~15 ≈ 150 < 168 cap
// imposed by 12 waves (3/SIMD) residency — no spill expected.
// ---------------------------------------------------------------------------
__global__ __launch_bounds__(768, 3) void gru_scan_kernel(
    const float* __restrict__ hidden,
    const float* __restrict__ rkf, const float* __restrict__ bf,
    const float* __restrict__ rkb, const float* __restrict__ bb,
    const _Float16* __restrict__ xp,
    float* __restrict__ out)
{
  const int b   = blockIdx.x;
  const int dir = blockIdx.y;
  const int j   = threadIdx.x;   // 0..767
  const float* RK = dir ? rkb : rkf;
  const float* BS = dir ? bb : bf;

  __shared__ __align__(16) _Float16 hbuf[H_SZ];  // h broadcast (f16)
  __shared__ __align__(16) float hp[C_SZ];       // h @ rkernel + rbias

  // load rkernel column j as 128 f16 pairs (coalesced across threads per k)
  h2v col[128];
  #pragma unroll
  for (int kk = 0; kk < 128; ++kk) {
    float f0 = RK[(2 * kk) * C_SZ + j];
    float f1 = RK[(2 * kk + 1) * C_SZ + j];
    h2v c2;
    c2[0] = (_Float16)f0;
    c2[1] = (_Float16)f1;
    col[kk] = c2;
  }
  const float rb = BS[C_SZ + j];   // bias row 1 (recurrent bias)

  float hreg = 0.f;
  if (j < H_SZ) {
    hreg = hidden[b * H_SZ + j];
    hbuf[j] = (_Float16)hreg;
  }

  const size_t xbase = ((size_t)dir * (B_SZ * T_SZ) + (size_t)b * T_SZ) * C_SZ;
  float xz_c = 0.f, xr_c = 0.f, xh_c = 0.f;
  if (j < H_SZ) {
    int t0 = dir ? (T_SZ - 1) : 0;
    const _Float16* xr0 = xp + xbase + (size_t)t0 * C_SZ;
    xz_c = (float)xr0[j];
    xr_c = (float)xr0[j + H_SZ];
    xh_c = (float)xr0[j + 2 * H_SZ];
  }
  __syncthreads();

  for (int s = 0; s < T_SZ; ++s) {
    // prefetch next step's x-projection row (hidden under the matvec)
    float xz_n = 0.f, xr_n = 0.f, xh_n = 0.f;
    if (j < H_SZ) {
      int sn = (s + 1 < T_SZ) ? (s + 1) : s;
      int tn = dir ? (T_SZ - 1 - sn) : sn;
      const _Float16* xrn = xp + xbase + (size_t)tn * C_SZ;
      xz_n = (float)xrn[j];
      xr_n = (float)xrn[j + H_SZ];
      xh_n = (float)xrn[j + 2 * H_SZ];
    }

    // hp[j] = sum_k h[k] * RK[k][j] + rbias[j]  (f16 dot2, f32 accumulate)
    float acc = rb;
    const float4* hb4 = (const float4*)hbuf;
    #pragma unroll
    for (int m = 0; m < 32; ++m) {
      float4 q = hb4[m];                 // uniform address -> LDS broadcast
      const h2v* hq = (const h2v*)&q;
      acc = dot2f(hq[0], col[4 * m + 0], acc);
      acc = dot2f(hq[1], col[4 * m + 1], acc);
      acc = dot2f(hq[2], col[4 * m + 2], acc);
      acc = dot2f(hq[3], col[4 * m + 3], acc);
    }
    hp[j] = acc;
    __syncthreads();

    if (j < H_SZ) {
      float z  = rcp_fast(1.f + __expf(-(xz_c + hp[j])));
      float r  = rcp_fast(1.f + __expf(-(xr_c + hp[j + H_SZ])));
      float pre = xh_c + r * hp[j + 2 * H_SZ];
      float e2 = __expf(2.f * pre);
      float hc = 1.f - 2.f * rcp_fast(e2 + 1.f);   // tanh(pre)
      hreg = z * hreg + (1.f - z) * hc;
      int t = dir ? (T_SZ - 1 - s) : s;
      out[((size_t)b * T_SZ + t) * (2 * H_SZ) + dir * H_SZ + j] = hreg;
      hbuf[j] = (_Float16)hreg;
    }
    __syncthreads();

    xz_c = xz_n; xr_c = xr_n; xh_c = xh_n;
  }

  if (j < H_SZ) {
    out[(size_t)(B_SZ * T_SZ) * (2 * H_SZ) + dir * (B_SZ * H_SZ) + b * H_SZ + j] = hreg;
  }
}

// ---------------------------------------------------------------------------
extern "C" void kernel_launch(void* const* d_in, const int* in_sizes, int n_in,
                              void* d_out, int out_size, void* d_ws, size_t ws_size,
                              hipStream_t stream) {
  const int*   x    = (const int*)d_in[0];
  const float* hid  = (const float*)d_in[1];
  const float* emb  = (const float*)d_in[2];
  const float* kf   = (const float*)d_in[3];
  const float* rkf  = (const float*)d_in[4];
  const float* bf   = (const float*)d_in[5];
  const float* kb   = (const float*)d_in[6];
  const float* rkb  = (const float*)d_in[7];
  const float* bb   = (const float*)d_in[8];
  float* out = (float*)d_out;

  _Float16* xp = (_Float16*)d_ws;  // [2][B*T][768] f16 = 100,663,296 bytes

  dim3 g1(16, 512, 2);
  xp_gemm_kernel<<<g1, 256, 0, stream>>>(x, emb, kf, bf, kb, bb, xp);

  dim3 g2(B_SZ, 2);
  gru_scan_kernel<<<g2, 768, 0, stream>>>(hid, rkf, bf, rkb, bb, xp, out);
}

// Round 6
// 1100.414 us; speedup vs baseline: 1.0233x; 1.0233x over previous
//
#include <hip/hip_runtime.h>
#include <hip/hip_bf16.h>

typedef _Float16 h2v __attribute__((ext_vector_type(2)));

#define B_SZ 64
#define T_SZ 512
#define E_SZ 256
#define H_SZ 256
#define C_SZ 768   // 3*H

__device__ __forceinline__ float dot2f(h2v a, h2v b, float c) {
#if __has_builtin(__builtin_amdgcn_fdot2)
  return __builtin_amdgcn_fdot2(a, b, c, false);
#else
  return c + (float)a[0] * (float)b[0] + (float)a[1] * (float)b[1];
#endif
}

__device__ __forceinline__ float rcp_fast(float x) {
  return __builtin_amdgcn_rcpf(x);
}

// quad_perm DPP adds (VALU pipe — keeps the 4-lane reduce off the LDS pipe)
__device__ __forceinline__ float dpp_add_x1(float v) {   // + lane^1
  int i = __builtin_bit_cast(int, v);
  int s = __builtin_amdgcn_update_dpp(i, i, 0xB1, 0xF, 0xF, true); // quad_perm [1,0,3,2]
  return v + __builtin_bit_cast(float, s);
}
__device__ __forceinline__ float dpp_add_x2(float v) {   // + lane^2
  int i = __builtin_bit_cast(int, v);
  int s = __builtin_amdgcn_update_dpp(i, i, 0x4E, 0xF, 0xF, true); // quad_perm [2,3,0,1]
  return v + __builtin_bit_cast(float, s);
}

// ---------------------------------------------------------------------------
// Kernel 1: xp[dir][row][c] = (emb[x[row]] @ kernel_dir)[c] + bias_dir[0][c]
// UNCHANGED this round (measured at ~75% of its fdot2 VALU floor; MFMA rewrite
// is next round's change).
// ---------------------------------------------------------------------------
__global__ __launch_bounds__(256) void xp_gemm_kernel(
    const int* __restrict__ x,
    const float* __restrict__ emb,
    const float* __restrict__ kf, const float* __restrict__ bf,
    const float* __restrict__ kb, const float* __restrict__ bb,
    _Float16* __restrict__ xp)
{
  const int ct  = blockIdx.x;   // 16 col tiles of 48
  const int rt  = blockIdx.y;   // 512 row tiles of 64
  const int dir = blockIdx.z;
  const float* Kp = dir ? kb : kf;
  const float* Bp = dir ? bb : bf;
  const int c0 = ct * 48;
  const int r0 = rt * 64;
  const int tid = threadIdx.x;

  __shared__ __align__(16) _Float16 As[64][264];
  __shared__ __align__(16) _Float16 Bs[48][264];

  for (int r = 0; r < 64; ++r) {
    int xi = x[r0 + r];
    As[r][tid] = (_Float16)emb[(size_t)xi * E_SZ + tid];
  }
  for (int i = tid; i < 48 * 256; i += 256) {
    int k = i / 48;
    int c = i - k * 48;
    Bs[c][k] = (_Float16)Kp[k * C_SZ + c0 + c];
  }
  __syncthreads();

  const int tr = tid >> 4;
  const int tc = tid & 15;
  float acc[4][3];
  #pragma unroll
  for (int i = 0; i < 4; ++i)
    #pragma unroll
    for (int j = 0; j < 3; ++j) acc[i][j] = 0.f;

  #pragma unroll
  for (int m = 0; m < 32; ++m) {
    float4 a4[4], b4[3];
    #pragma unroll
    for (int i = 0; i < 4; ++i) a4[i] = *(const float4*)&As[tr * 4 + i][m * 8];
    #pragma unroll
    for (int j = 0; j < 3; ++j) b4[j] = *(const float4*)&Bs[tc + 16 * j][m * 8];
    #pragma unroll
    for (int i = 0; i < 4; ++i) {
      const h2v* ah = (const h2v*)&a4[i];
      #pragma unroll
      for (int j = 0; j < 3; ++j) {
        const h2v* bh = (const h2v*)&b4[j];
        #pragma unroll
        for (int p = 0; p < 4; ++p) acc[i][j] = dot2f(ah[p], bh[p], acc[i][j]);
      }
    }
  }

  #pragma unroll
  for (int j = 0; j < 3; ++j) {
    int c = c0 + tc + 16 * j;
    float bias = Bp[c];
    #pragma unroll
    for (int i = 0; i < 4; ++i) {
      int r = r0 + tr * 4 + i;
      xp[((size_t)dir * (B_SZ * T_SZ) + r) * C_SZ + c] = (_Float16)(acc[i][j] + bias);
    }
  }
}

// ---------------------------------------------------------------------------
// Kernel 2: GRU scan, quad-split K.
//  - lane q=tid&3 owns k-slice [64q,64q+64); quad owns outputs (tid&~3)+0..3
//  - col regs: 4 outputs x 32 h2v = 128 VGPRs (amdgpu_waves_per_eu(3,3) pins
//    the budget at 512/3=170 so the allocator keeps them resident; round-4
//    showed launch_bounds alone let it drop to 84 VGPR + remat)
//  - h in LDS as 4 slices of 64 f16 at 144B stride: 8 ds_read_b128/thread/step
//    (was 32 broadcast reads), 4 distinct addrs/instr, banks 4i+{0,4,8,12} ->
//    conflict-free
//  - 4-lane reduce via DPP quad_perm adds (VALU), select own output, +bias
// ---------------------------------------------------------------------------
__global__ __launch_bounds__(768) __attribute__((amdgpu_waves_per_eu(3, 3)))
void gru_scan_kernel(
    const float* __restrict__ hidden,
    const float* __restrict__ rkf, const float* __restrict__ bf,
    const float* __restrict__ rkb, const float* __restrict__ bb,
    const _Float16* __restrict__ xp,
    float* __restrict__ out)
{
  const int b   = blockIdx.x;
  const int dir = blockIdx.y;
  const int tid = threadIdx.x;   // 0..767; output column j = tid
  const int q   = tid & 3;       // k-slice owner within quad
  const float* RK = dir ? rkb : rkf;
  const float* BS = dir ? bb : bf;

  __shared__ __align__(16) _Float16 hbuf[4 * 72]; // slice q at elem 72*q (144B stride)
  __shared__ __align__(16) float hp[C_SZ];

  // col[o][m] = RK[64q+2m .. +1][ (tid&~3)+o ] as f16 pair (one-time, L2/L3-hot)
  h2v col[4][32];
  const int cbase = tid & ~3;
  #pragma unroll
  for (int o = 0; o < 4; ++o) {
    #pragma unroll
    for (int m = 0; m < 32; ++m) {
      int k = 64 * q + 2 * m;
      h2v c2;
      c2[0] = (_Float16)RK[(size_t)k * C_SZ + cbase + o];
      c2[1] = (_Float16)RK[(size_t)(k + 1) * C_SZ + cbase + o];
      col[o][m] = c2;
    }
  }
  const float rb = BS[C_SZ + tid];   // recurrent bias for output j=tid

  float hreg = 0.f;
  if (tid < H_SZ) {
    hreg = hidden[b * H_SZ + tid];
    hbuf[72 * (tid >> 6) + (tid & 63)] = (_Float16)hreg;
  }

  const size_t xbase = ((size_t)dir * (B_SZ * T_SZ) + (size_t)b * T_SZ) * C_SZ;
  float xz_c = 0.f, xr_c = 0.f, xh_c = 0.f;
  if (tid < H_SZ) {
    int t0 = dir ? (T_SZ - 1) : 0;
    const _Float16* xr0 = xp + xbase + (size_t)t0 * C_SZ;
    xz_c = (float)xr0[tid];
    xr_c = (float)xr0[tid + H_SZ];
    xh_c = (float)xr0[tid + 2 * H_SZ];
  }
  __syncthreads();

  for (int s = 0; s < T_SZ; ++s) {
    // prefetch next step's xp row (hides under the matvec)
    float xz_n = 0.f, xr_n = 0.f, xh_n = 0.f;
    if (tid < H_SZ) {
      int sn = (s + 1 < T_SZ) ? (s + 1) : s;
      int tn = dir ? (T_SZ - 1 - sn) : sn;
      const _Float16* xrn = xp + xbase + (size_t)tn * C_SZ;
      xz_n = (float)xrn[tid];
      xr_n = (float)xrn[tid + H_SZ];
      xh_n = (float)xrn[tid + 2 * H_SZ];
    }

    // partial dots over own k-slice for the quad's 4 outputs
    float acc0 = 0.f, acc1 = 0.f, acc2 = 0.f, acc3 = 0.f;
    const float4* hsl = (const float4*)(hbuf + 72 * q);
    #pragma unroll
    for (int i = 0; i < 8; ++i) {
      float4 c = hsl[i];                  // 8 f16 of slice, distributed read
      const h2v* hv = (const h2v*)&c;
      #pragma unroll
      for (int p = 0; p < 4; ++p) {
        int m = 4 * i + p;
        acc0 = dot2f(hv[p], col[0][m], acc0);
        acc1 = dot2f(hv[p], col[1][m], acc1);
        acc2 = dot2f(hv[p], col[2][m], acc2);
        acc3 = dot2f(hv[p], col[3][m], acc3);
      }
    }
    // quad butterfly (VALU): every lane gets all 4 totals, keep own
    acc0 = dpp_add_x2(dpp_add_x1(acc0));
    acc1 = dpp_add_x2(dpp_add_x1(acc1));
    acc2 = dpp_add_x2(dpp_add_x1(acc2));
    acc3 = dpp_add_x2(dpp_add_x1(acc3));
    float sel01 = (q & 1) ? acc1 : acc0;
    float sel23 = (q & 1) ? acc3 : acc2;
    float val   = (q & 2) ? sel23 : sel01;
    hp[tid] = val + rb;
    __syncthreads();

    if (tid < H_SZ) {
      float z  = rcp_fast(1.f + __expf(-(xz_c + hp[tid])));
      float r  = rcp_fast(1.f + __expf(-(xr_c + hp[tid + H_SZ])));
      float pre = xh_c + r * hp[tid + 2 * H_SZ];
      float e2 = __expf(2.f * pre);
      float hc = 1.f - 2.f * rcp_fast(e2 + 1.f);   // tanh(pre)
      hreg = z * hreg + (1.f - z) * hc;
      int t = dir ? (T_SZ - 1 - s) : s;
      out[((size_t)b * T_SZ + t) * (2 * H_SZ) + dir * H_SZ + tid] = hreg;
      hbuf[72 * (tid >> 6) + (tid & 63)] = (_Float16)hreg;
    }
    __syncthreads();

    xz_c = xz_n; xr_c = xr_n; xh_c = xh_n;
  }

  if (tid < H_SZ) {
    out[(size_t)(B_SZ * T_SZ) * (2 * H_SZ) + dir * (B_SZ * H_SZ) + b * H_SZ + tid] = hreg;
  }
}

// ---------------------------------------------------------------------------
extern "C" void kernel_launch(void* const* d_in, const int* in_sizes, int n_in,
                              void* d_out, int out_size, void* d_ws, size_t ws_size,
                              hipStream_t stream) {
  const int*   x    = (const int*)d_in[0];
  const float* hid  = (const float*)d_in[1];
  const float* emb  = (const float*)d_in[2];
  const float* kf   = (const float*)d_in[3];
  const float* rkf  = (const float*)d_in[4];
  const float* bf   = (const float*)d_in[5];
  const float* kb   = (const float*)d_in[6];
  const float* rkb  = (const float*)d_in[7];
  const float* bb   = (const float*)d_in[8];
  float* out = (float*)d_out;

  _Float16* xp = (_Float16*)d_ws;  // [2][B*T][768] f16 = 100,663,296 bytes

  dim3 g1(16, 512, 2);
  xp_gemm_kernel<<<g1, 256, 0, stream>>>(x, emb, kf, bf, kb, bb, xp);

  dim3 g2(B_SZ, 2);
  gru_scan_kernel<<<g2, 768, 0, stream>>>(hid, rkf, bf, rkb, bb, xp, out);
}

// Round 8
// 1090.212 us; speedup vs baseline: 1.0329x; 1.0094x over previous
//
#include <hip/hip_runtime.h>
#include <hip/hip_bf16.h>

typedef _Float16 h2v __attribute__((ext_vector_type(2)));

#define B_SZ 64
#define T_SZ 512
#define E_SZ 256
#define H_SZ 256
#define C_SZ 768   // 3*H

__device__ __forceinline__ float dot2f(h2v a, h2v b, float c) {
#if __has_builtin(__builtin_amdgcn_fdot2)
  return __builtin_amdgcn_fdot2(a, b, c, false);
#else
  return c + (float)a[0] * (float)b[0] + (float)a[1] * (float)b[1];
#endif
}

__device__ __forceinline__ float rcp_fast(float x) {
  return __builtin_amdgcn_rcpf(x);
}

// quad_perm DPP adds (VALU pipe — keeps the 4-lane reduce off the LDS pipe)
__device__ __forceinline__ float dpp_add_x1(float v) {   // + lane^1
  int i = __builtin_bit_cast(int, v);
  int s = __builtin_amdgcn_update_dpp(i, i, 0xB1, 0xF, 0xF, true); // quad_perm [1,0,3,2]
  return v + __builtin_bit_cast(float, s);
}
__device__ __forceinline__ float dpp_add_x2(float v) {   // + lane^2
  int i = __builtin_bit_cast(int, v);
  int s = __builtin_amdgcn_update_dpp(i, i, 0x4E, 0xF, 0xF, true); // quad_perm [2,3,0,1]
  return v + __builtin_bit_cast(float, s);
}

// ---------------------------------------------------------------------------
// Kernel 1: xp[dir][row][c] = (emb[x[row]] @ kernel_dir)[c] + bias_dir[0][c]
// UNCHANGED (measured ~441us, ~75% of its fdot2 VALU floor; MFMA rewrite is
// next round's isolated change).
// ---------------------------------------------------------------------------
__global__ __launch_bounds__(256) void xp_gemm_kernel(
    const int* __restrict__ x,
    const float* __restrict__ emb,
    const float* __restrict__ kf, const float* __restrict__ bf,
    const float* __restrict__ kb, const float* __restrict__ bb,
    _Float16* __restrict__ xp)
{
  const int ct  = blockIdx.x;   // 16 col tiles of 48
  const int rt  = blockIdx.y;   // 512 row tiles of 64
  const int dir = blockIdx.z;
  const float* Kp = dir ? kb : kf;
  const float* Bp = dir ? bb : bf;
  const int c0 = ct * 48;
  const int r0 = rt * 64;
  const int tid = threadIdx.x;

  __shared__ __align__(16) _Float16 As[64][264];
  __shared__ __align__(16) _Float16 Bs[48][264];

  for (int r = 0; r < 64; ++r) {
    int xi = x[r0 + r];
    As[r][tid] = (_Float16)emb[(size_t)xi * E_SZ + tid];
  }
  for (int i = tid; i < 48 * 256; i += 256) {
    int k = i / 48;
    int c = i - k * 48;
    Bs[c][k] = (_Float16)Kp[k * C_SZ + c0 + c];
  }
  __syncthreads();

  const int tr = tid >> 4;
  const int tc = tid & 15;
  float acc[4][3];
  #pragma unroll
  for (int i = 0; i < 4; ++i)
    #pragma unroll
    for (int j = 0; j < 3; ++j) acc[i][j] = 0.f;

  #pragma unroll
  for (int m = 0; m < 32; ++m) {
    float4 a4[4], b4[3];
    #pragma unroll
    for (int i = 0; i < 4; ++i) a4[i] = *(const float4*)&As[tr * 4 + i][m * 8];
    #pragma unroll
    for (int j = 0; j < 3; ++j) b4[j] = *(const float4*)&Bs[tc + 16 * j][m * 8];
    #pragma unroll
    for (int i = 0; i < 4; ++i) {
      const h2v* ah = (const h2v*)&a4[i];
      #pragma unroll
      for (int j = 0; j < 3; ++j) {
        const h2v* bh = (const h2v*)&b4[j];
        #pragma unroll
        for (int p = 0; p < 4; ++p) acc[i][j] = dot2f(ah[p], bh[p], acc[i][j]);
      }
    }
  }

  #pragma unroll
  for (int j = 0; j < 3; ++j) {
    int c = c0 + tc + 16 * j;
    float bias = Bp[c];
    #pragma unroll
    for (int i = 0; i < 4; ++i) {
      int r = r0 + tr * 4 + i;
      xp[((size_t)dir * (B_SZ * T_SZ) + r) * C_SZ + c] = (_Float16)(acc[i][j] + bias);
    }
  }
}

// ---------------------------------------------------------------------------
// Kernel 2: GRU scan, quad-split K + REGISTER-PINNED weights.
// Round-6 post-mortem: VGPR=84 proved the compiler rematerialized col[] from
// global every step (~256 L2 loads/thread/step ≈ observed 3047 cy/step).
// Fix: volatile loads (cannot be re-executed) + opaque asm touch (origin
// hidden from allocator) => col MUST stay in VGPRs (budget 170 via
// waves_per_eu(3,3); live set ~163). Scratch spill would falsify: watch dur.
// ---------------------------------------------------------------------------
__global__ __launch_bounds__(768) __attribute__((amdgpu_waves_per_eu(3, 3)))
void gru_scan_kernel(
    const float* __restrict__ hidden,
    const float* __restrict__ rkf, const float* __restrict__ bf,
    const float* __restrict__ rkb, const float* __restrict__ bb,
    const _Float16* __restrict__ xp,
    float* __restrict__ out)
{
  const int b   = blockIdx.x;
  const int dir = blockIdx.y;
  const int tid = threadIdx.x;   // 0..767; output column j = tid
  const int q   = tid & 3;       // k-slice owner within quad
  const float* RK = dir ? rkb : rkf;
  const float* BS = dir ? bb : bf;

  __shared__ __align__(16) _Float16 hbuf[4 * 72]; // slice q at elem 72*q (144B stride)
  __shared__ __align__(16) float hp[C_SZ];

  // col[o][m] = RK[64q+2m .. +1][ (tid&~3)+o ] as f16 pair.
  // volatile: loads execute exactly once (no remat); asm: value origin opaque.
  h2v col[4][32];
  const int cbase = tid & ~3;
  #pragma unroll
  for (int o = 0; o < 4; ++o) {
    #pragma unroll
    for (int m = 0; m < 32; ++m) {
      int k = 64 * q + 2 * m;
      volatile const float* rk0 = RK + (size_t)k * C_SZ + cbase + o;
      volatile const float* rk1 = RK + (size_t)(k + 1) * C_SZ + cbase + o;
      h2v c2;
      c2[0] = (_Float16)(*rk0);
      c2[1] = (_Float16)(*rk1);
      col[o][m] = c2;
    }
  }
  #pragma unroll
  for (int o = 0; o < 4; ++o)
    #pragma unroll
    for (int m = 0; m < 32; ++m)
      asm volatile("" : "+v"(col[o][m]));

  const float rb = BS[C_SZ + tid];   // recurrent bias for output j=tid

  float hreg = 0.f;
  if (tid < H_SZ) {
    hreg = hidden[b * H_SZ + tid];
    hbuf[72 * (tid >> 6) + (tid & 63)] = (_Float16)hreg;
  }

  const size_t xbase = ((size_t)dir * (B_SZ * T_SZ) + (size_t)b * T_SZ) * C_SZ;
  float xz_c = 0.f, xr_c = 0.f, xh_c = 0.f;
  if (tid < H_SZ) {
    int t0 = dir ? (T_SZ - 1) : 0;
    const _Float16* xr0 = xp + xbase + (size_t)t0 * C_SZ;
    xz_c = (float)xr0[tid];
    xr_c = (float)xr0[tid + H_SZ];
    xh_c = (float)xr0[tid + 2 * H_SZ];
  }
  __syncthreads();

  for (int s = 0; s < T_SZ; ++s) {
    // prefetch next step's xp row (hides under the matvec)
    float xz_n = 0.f, xr_n = 0.f, xh_n = 0.f;
    if (tid < H_SZ) {
      int sn = (s + 1 < T_SZ) ? (s + 1) : s;
      int tn = dir ? (T_SZ - 1 - sn) : sn;
      const _Float16* xrn = xp + xbase + (size_t)tn * C_SZ;
      xz_n = (float)xrn[tid];
      xr_n = (float)xrn[tid + H_SZ];
      xh_n = (float)xrn[tid + 2 * H_SZ];
    }

    // partial dots over own k-slice for the quad's 4 outputs
    float acc0 = 0.f, acc1 = 0.f, acc2 = 0.f, acc3 = 0.f;
    const float4* hsl = (const float4*)(hbuf + 72 * q);
    #pragma unroll
    for (int i = 0; i < 8; ++i) {
      float4 c = hsl[i];                  // 8 f16 of slice, distributed read
      const h2v* hv = (const h2v*)&c;
      #pragma unroll
      for (int p = 0; p < 4; ++p) {
        int m = 4 * i + p;
        acc0 = dot2f(hv[p], col[0][m], acc0);
        acc1 = dot2f(hv[p], col[1][m], acc1);
        acc2 = dot2f(hv[p], col[2][m], acc2);
        acc3 = dot2f(hv[p], col[3][m], acc3);
      }
    }
    // quad butterfly (VALU): every lane gets all 4 totals, keep own
    acc0 = dpp_add_x2(dpp_add_x1(acc0));
    acc1 = dpp_add_x2(dpp_add_x1(acc1));
    acc2 = dpp_add_x2(dpp_add_x1(acc2));
    acc3 = dpp_add_x2(dpp_add_x1(acc3));
    float sel01 = (q & 1) ? acc1 : acc0;
    float sel23 = (q & 1) ? acc3 : acc2;
    float val   = (q & 2) ? sel23 : sel01;
    hp[tid] = val + rb;
    __syncthreads();

    if (tid < H_SZ) {
      float z  = rcp_fast(1.f + __expf(-(xz_c + hp[tid])));
      float r  = rcp_fast(1.f + __expf(-(xr_c + hp[tid + H_SZ])));
      float pre = xh_c + r * hp[tid + 2 * H_SZ];
      float e2 = __expf(2.f * pre);
      float hc = 1.f - 2.f * rcp_fast(e2 + 1.f);   // tanh(pre)
      hreg = z * hreg + (1.f - z) * hc;
      int t = dir ? (T_SZ - 1 - s) : s;
      out[((size_t)b * T_SZ + t) * (2 * H_SZ) + dir * H_SZ + tid] = hreg;
      hbuf[72 * (tid >> 6) + (tid & 63)] = (_Float16)hreg;
    }
    __syncthreads();

    xz_c = xz_n; xr_c = xr_n; xh_c = xh_n;
  }

  if (tid < H_SZ) {
    out[(size_t)(B_SZ * T_SZ) * (2 * H_SZ) + dir * (B_SZ * H_SZ) + b * H_SZ + tid] = hreg;
  }
}

// ---------------------------------------------------------------------------
extern "C" void kernel_launch(void* const* d_in, const int* in_sizes, int n_in,
                              void* d_out, int out_size, void* d_ws, size_t ws_size,
                              hipStream_t stream) {
  const int*   x    = (const int*)d_in[0];
  const float* hid  = (const float*)d_in[1];
  const float* emb  = (const float*)d_in[2];
  const float* kf   = (const float*)d_in[3];
  const float* rkf  = (const float*)d_in[4];
  const float* bf   = (const float*)d_in[5];
  const float* kb   = (const float*)d_in[6];
  const float* rkb  = (const float*)d_in[7];
  const float* bb   = (const float*)d_in[8];
  float* out = (float*)d_out;

  _Float16* xp = (_Float16*)d_ws;  // [2][B*T][768] f16 = 100,663,296 bytes

  dim3 g1(16, 512, 2);
  xp_gemm_kernel<<<g1, 256, 0, stream>>>(x, emb, kf, bf, kb, bb, xp);

  dim3 g2(B_SZ, 2);
  gru_scan_kernel<<<g2, 768, 0, stream>>>(hid, rkf, bf, rkb, bb, xp, out);
}